// Round 8
// baseline (52.460 us; speedup 1.0000x reference)
//
#include <hip/hip_runtime.h>
#include <hip/hip_bf16.h>

typedef __attribute__((ext_vector_type(8))) short bf16x8;
typedef __attribute__((ext_vector_type(4))) float f32x4;

#define K_DIM 256
#define N_DIM 512
#define BM 32
#define M_DIM 65536
#define TPB 8                        // x-tiles per block
#define GRID (M_DIM / BM / TPB)      // 256 blocks = 1 per CU

// round-to-nearest-even fp32 -> bf16 bits
__device__ __forceinline__ unsigned short f2bf(float f) {
    unsigned int u = __float_as_uint(f);
    unsigned int r = (u + 0x7fffu + ((u >> 16) & 1u)) >> 16;
    return (unsigned short)r;
}

// barrier that does NOT drain global stores/loads: LDS-visibility only.
__device__ __forceinline__ void barrier_lds() {
    asm volatile("s_waitcnt lgkmcnt(0)" ::: "memory");
    __builtin_amdgcn_s_barrier();
}

// Kernel 1: clusters fp32 -> bf16 ARRANGED per-(wc,ks,n,lane) fragment order
// (wave wc owns 64 cluster cols) + fp32 row norms.
// arranged[wc][ks][n][L][ko] = clusters[wc*64 + n*16 + (L&15)][ks*32 + (L>>4)*8 + ko]
__global__ __launch_bounds__(256) void prep_clusters(
        const float* __restrict__ clusters,
        unsigned short* __restrict__ cba,
        float* __restrict__ csq) {
    const int row = blockIdx.x;   // 512 cluster rows
    const int t = threadIdx.x;    // 256 = K_DIM
    const float v = clusters[row * K_DIM + t];
    const int wc = row >> 6, n = (row >> 4) & 3, r = row & 15;
    const int ks = t >> 5, kh = (t >> 3) & 3, ko = t & 7;
    cba[(size_t)wc * 16384 + ks * 2048 + n * 512 + (kh * 16 + r) * 8 + ko] = f2bf(v);
    float s = v * v;
    #pragma unroll
    for (int m = 1; m < 64; m <<= 1) s += __shfl_xor(s, m);
    __shared__ float red[4];
    if ((t & 63) == 0) red[t >> 6] = s;
    __syncthreads();
    if (t == 0) csq[row] = red[0] + red[1] + red[2] + red[3];
}

// Kernel 2: clusters permanently in registers (B operand, 128 VGPR/wave);
// x streamed through double-buffered swizzled LDS (A operand); one lgkm-only
// barrier per tile. Operand order mfma(x, clusters): lane holds 16-contiguous
// cluster cols -> stores are 64B-segment coalesced (4 segs/instr, not 64).
__global__ __launch_bounds__(512, 2) void cluster_q(
        const float* __restrict__ x,
        const unsigned short* __restrict__ cba,
        const float* __restrict__ csq,
        float* __restrict__ out) {
    __shared__ __align__(16) unsigned short xa[2][BM * K_DIM]; // 2 x 16 KB, XOR-swizzled
    __shared__ float xsq[2][BM];
    __shared__ __align__(16) float csql[N_DIM];
    __shared__ float rsum[2][8][BM];

    const int t = threadIdx.x;
    const int lane = t & 63;
    const int wc = t >> 6;        // wave 0..7 = 64-col cluster group

    // ---- prologue: this wave's cluster slice -> registers, permanently ----
    const unsigned short* gsrc = cba + (size_t)wc * 16384;
    bf16x8 breg[8][4];
    #pragma unroll
    for (int ks = 0; ks < 8; ++ks)
        #pragma unroll
        for (int n = 0; n < 4; ++n)
            breg[ks][n] = *reinterpret_cast<const bf16x8*>(
                              gsrc + ks * 2048 + n * 512 + lane * 8);

    csql[t] = csq[t];   // t in [0,512)

    const size_t base = (size_t)blockIdx.x * (TPB * BM);

    float4 xr0, xr1, xr2, xr3;
    // load tile 0 (wave wc owns rows wc, wc+8, wc+16, wc+24)
    {
        const float4* xp = reinterpret_cast<const float4*>(x + (base + wc) * K_DIM);
        xr0 = xp[lane]; xr1 = xp[512 + lane]; xr2 = xp[1024 + lane]; xr3 = xp[1536 + lane];
    }
    // stage tile 0 into buffer 0
    {
        const float4 vv[4] = {xr0, xr1, xr2, xr3};
        #pragma unroll
        for (int p = 0; p < 4; ++p) {
            const int row = wc + p * 8;
            const float4 v = vv[p];
            float s = v.x * v.x + v.y * v.y + v.z * v.z + v.w * v.w;
            #pragma unroll
            for (int m = 1; m < 64; m <<= 1) s += __shfl_xor(s, m);
            if (lane == 0) xsq[0][row] = s;
            const ushort4 pk = make_ushort4(f2bf(v.x), f2bf(v.y), f2bf(v.z), f2bf(v.w));
            const int swz = (lane * 8) ^ ((row & 7) << 4);
            *reinterpret_cast<ushort4*>(
                reinterpret_cast<char*>(xa[0]) + row * 512 + swz) = pk;
        }
    }
    // issue tile 1's loads (fly across the barrier; staged at iteration 0)
    {
        const float4* xp = reinterpret_cast<const float4*>(x + (base + BM + wc) * K_DIM);
        xr0 = xp[lane]; xr1 = xp[512 + lane]; xr2 = xp[1024 + lane]; xr3 = xp[1536 + lane];
    }
    barrier_lds();

    for (int it = 0; it < TPB; ++it) {
        const int cur = it & 1, nxt = cur ^ 1;
        const size_t rowbase = base + (size_t)it * BM;

        // ---- stage tile it+1 into buffer nxt ----
        if (it + 1 < TPB) {
            const float4 vv[4] = {xr0, xr1, xr2, xr3};
            #pragma unroll
            for (int p = 0; p < 4; ++p) {
                const int row = wc + p * 8;
                const float4 v = vv[p];
                float s = v.x * v.x + v.y * v.y + v.z * v.z + v.w * v.w;
                #pragma unroll
                for (int m = 1; m < 64; m <<= 1) s += __shfl_xor(s, m);
                if (lane == 0) xsq[nxt][row] = s;
                const ushort4 pk = make_ushort4(f2bf(v.x), f2bf(v.y), f2bf(v.z), f2bf(v.w));
                const int swz = (lane * 8) ^ ((row & 7) << 4);
                *reinterpret_cast<ushort4*>(
                    reinterpret_cast<char*>(xa[nxt]) + row * 512 + swz) = pk;
            }
        }
        // ---- issue tile it+2's loads ----
        if (it + 2 < TPB) {
            const float4* xp = reinterpret_cast<const float4*>(
                                   x + (rowbase + 2 * BM + wc) * K_DIM);
            xr0 = xp[lane]; xr1 = xp[512 + lane]; xr2 = xp[1024 + lane]; xr3 = xp[1536 + lane];
        }
        __builtin_amdgcn_sched_barrier(0);   // pin staging+load issue above K-loop

        // ---- K-loop: LDS (A=x) x registers (B=clusters) ----
        f32x4 acc[2][4];
        #pragma unroll
        for (int m = 0; m < 2; ++m)
            #pragma unroll
            for (int n = 0; n < 4; ++n)
                acc[m][n] = (f32x4){0.f, 0.f, 0.f, 0.f};

        const char* xab = reinterpret_cast<const char*>(xa[cur]);
        #pragma unroll
        for (int ks = 0; ks < 8; ++ks) {
            const int r0 = (lane & 15);
            const int r1 = 16 + (lane & 15);
            const int c0 = (ks * 64 + (lane >> 4) * 16) ^ ((r0 & 7) << 4);
            const int c1 = (ks * 64 + (lane >> 4) * 16) ^ ((r1 & 7) << 4);
            const bf16x8 xm0 = *reinterpret_cast<const bf16x8*>(xab + r0 * 512 + c0);
            const bf16x8 xm1 = *reinterpret_cast<const bf16x8*>(xab + r1 * 512 + c1);
            #pragma unroll
            for (int n = 0; n < 4; ++n) {
                acc[0][n] = __builtin_amdgcn_mfma_f32_16x16x32_bf16(xm0, breg[ks][n], acc[0][n], 0, 0, 0);
                acc[1][n] = __builtin_amdgcn_mfma_f32_16x16x32_bf16(xm1, breg[ks][n], acc[1][n], 0, 0, 0);
            }
        }

        // ---- epilogue: D[xrow][ccol]; lane: ccol = wc*64+n*16+(lane&15),
        //      xrow = m*16 + (lane>>4)*4 + j ----
        float xs1[2][4];
        #pragma unroll
        for (int m = 0; m < 2; ++m)
            #pragma unroll
            for (int j = 0; j < 4; ++j)
                xs1[m][j] = 1.f + xsq[cur][m * 16 + (lane >> 4) * 4 + j];

        float part[2][4];
        #pragma unroll
        for (int m = 0; m < 2; ++m)
            #pragma unroll
            for (int j = 0; j < 4; ++j) part[m][j] = 0.f;

        #pragma unroll
        for (int m = 0; m < 2; ++m) {
            #pragma unroll
            for (int n = 0; n < 4; ++n) {
                const float cs = csql[wc * 64 + n * 16 + (lane & 15)];
                #pragma unroll
                for (int j = 0; j < 4; ++j) {
                    const float q = __builtin_amdgcn_rcpf(
                                        fmaf(-2.f, acc[m][n][j], xs1[m][j] + cs));
                    acc[m][n][j] = q;
                    part[m][j] += q;
                }
            }
        }
        // row sums: 16-lane butterfly (cols within group), then cross-wave
        #pragma unroll
        for (int m = 0; m < 2; ++m)
            #pragma unroll
            for (int j = 0; j < 4; ++j) {
                float s = part[m][j];
                s += __shfl_xor(s, 1);
                s += __shfl_xor(s, 2);
                s += __shfl_xor(s, 4);
                s += __shfl_xor(s, 8);
                if ((lane & 15) == 0)
                    rsum[cur][wc][m * 16 + (lane >> 4) * 4 + j] = s;
            }
        // the ONLY barrier per tile: lgkm-only (global stores stay in flight).
        barrier_lds();

        // normalize + store: per instr 4 x 64B contiguous segments
        #pragma unroll
        for (int m = 0; m < 2; ++m) {
            #pragma unroll
            for (int j = 0; j < 4; ++j) {
                const int rloc = m * 16 + (lane >> 4) * 4 + j;
                const float inv = __builtin_amdgcn_rcpf(
                    ((rsum[cur][0][rloc] + rsum[cur][1][rloc]) +
                     (rsum[cur][2][rloc] + rsum[cur][3][rloc])) +
                    ((rsum[cur][4][rloc] + rsum[cur][5][rloc]) +
                     (rsum[cur][6][rloc] + rsum[cur][7][rloc])));
                float* orow = out + (rowbase + rloc) * N_DIM + wc * 64 + (lane & 15);
                #pragma unroll
                for (int n = 0; n < 4; ++n)
                    orow[n * 16] = acc[m][n][j] * inv;
            }
        }
    }
}

extern "C" void kernel_launch(void* const* d_in, const int* in_sizes, int n_in,
                              void* d_out, int out_size, void* d_ws, size_t ws_size,
                              hipStream_t stream) {
    const float* x        = (const float*)d_in[0];
    const float* clusters = (const float*)d_in[1];
    float* out = (float*)d_out;
    unsigned short* cba = (unsigned short*)d_ws;                      // 256 KB arranged
    float* csq = (float*)((char*)d_ws + (size_t)N_DIM * K_DIM * 2);   // + 2 KB
    prep_clusters<<<N_DIM, K_DIM, 0, stream>>>(clusters, cba, csq);
    cluster_q<<<GRID, 512, 0, stream>>>(x, cba, csq, out);
}